// Round 1
// baseline (4959.543 us; speedup 1.0000x reference)
//
#include <hip/hip_runtime.h>
#include <stdint.h>

#define T_STEPS 128
#define BATCH   256

typedef __attribute__((ext_vector_type(8))) short bfrag8;   // 8 x bf16 (guide-verified operand type)
typedef __attribute__((ext_vector_type(4))) float f32x4;

// ---------------- LDS layout (persistent kernel) ----------------
// 4 gate-weight slices [32 rows x 520], 2 out-weight slices [8 x 520] (ushort),
// then fp32: staging [64][33], c0[512], c1[512], b1[32], b2[8]
#define L_WIH0 0
#define L_WHH0 16640
#define L_WC1  33280
#define L_WHH1 49920
#define L_W2   66560
#define L_WOUT 70720
#define L_STG_B 149760
#define L_C0_B  158208
#define L_C1_B  160256
#define L_B1_B  162304
#define L_B2_B  162432
#define SMEM_BYTES 162464

static __device__ __forceinline__ unsigned short f2bf(float f){
  union { float f; unsigned u; } v; v.f = f;
  return (unsigned short)((v.u + 0x7FFFu + ((v.u >> 16) & 1u)) >> 16);  // RNE
}
static __device__ __forceinline__ float sigm(float x){
  return 1.f / (1.f + __expf(-x));
}
static __device__ __forceinline__ float tanh_(float x){
  x = fminf(15.f, fmaxf(-15.f, x));
  float e = __expf(2.f * x);
  return 1.f - 2.f / (e + 1.f);
}
static __device__ __forceinline__ f32x4 mfma16(bfrag8 a, bfrag8 b, f32x4 c){
  return __builtin_amdgcn_mfma_f32_16x16x32_bf16(a, b, c, 0, 0, 0);
}

// ---------------- prep kernels ----------------
__global__ void cast_f32_bf16(const float* __restrict__ in, unsigned short* __restrict__ out, int n4){
  int i = blockIdx.x * blockDim.x + threadIdx.x;
  if (i < n4){
    float4 v = ((const float4*)in)[i];
    ushort4 o;
    o.x = f2bf(v.x); o.y = f2bf(v.y); o.z = f2bf(v.z); o.w = f2bf(v.w);
    ((ushort4*)out)[i] = o;
  }
}

// C[M x N] = A[M x K] @ B[K x N], fp32 in, bf16 out. N,K = 512 here.
__global__ void __launch_bounds__(256) gemm_combo(const float* __restrict__ A, const float* __restrict__ B,
                                                  unsigned short* __restrict__ C, int M, int N, int K){
  __shared__ float As[64][17];
  __shared__ float Bs[16][68];
  int col0 = blockIdx.x * 64;
  int row0 = blockIdx.y * 64;
  int tid = threadIdx.x;
  int tx = tid & 15, ty = tid >> 4;
  float acc[4][4] = {};
  for (int kp = 0; kp < K; kp += 16){
    for (int i = tid; i < 64*16; i += 256){
      int r = i >> 4, c = i & 15;
      As[r][c] = A[(size_t)(row0 + r) * K + kp + c];
    }
    for (int i = tid; i < 16*64; i += 256){
      int r = i >> 6, c = i & 63;
      Bs[r][c] = B[(size_t)(kp + r) * N + col0 + c];
    }
    __syncthreads();
    #pragma unroll
    for (int kk = 0; kk < 16; kk++){
      float a[4], b[4];
      #pragma unroll
      for (int i = 0; i < 4; i++) a[i] = As[ty*4 + i][kk];
      #pragma unroll
      for (int j = 0; j < 4; j++) b[j] = Bs[kk][tx*4 + j];
      #pragma unroll
      for (int i = 0; i < 4; i++)
        #pragma unroll
        for (int j = 0; j < 4; j++) acc[i][j] += a[i] * b[j];
    }
    __syncthreads();
  }
  for (int i = 0; i < 4; i++)
    for (int j = 0; j < 4; j++)
      C[(size_t)(row0 + ty*4 + i) * N + col0 + tx*4 + j] = f2bf(acc[i][j]);
}

// B1[2048] = b_ih + b_hh + W_ih1 @ b_out ; B2[512] = W_out @ b_out + b_out
__global__ void bias_prep(const float* __restrict__ wih1, const float* __restrict__ bih,
                          const float* __restrict__ bhh, const float* __restrict__ wout,
                          const float* __restrict__ bout, float* __restrict__ B1, float* __restrict__ B2){
  int t = blockIdx.x * blockDim.x + threadIdx.x;
  if (t < 2048){
    float s = bih[t] + bhh[t];
    for (int k = 0; k < 512; k++) s += wih1[(size_t)t*512 + k] * bout[k];
    B1[t] = s;
  } else if (t < 2560){
    int n = t - 2048;
    float s = bout[n];
    for (int k = 0; k < 512; k++) s += wout[(size_t)n*512 + k] * bout[k];
    B2[n] = s;
  }
}

// ---------------- persistent recurrence kernel ----------------
// grid 256 = 4 batch-groups x 64 column-slices; 1 WG/CU; 256 thr = 4 waves.
__global__ void __launch_bounds__(256, 1) fflstm_persist(
    const unsigned short* __restrict__ xb,     // [T][256][512] bf16
    const unsigned short* __restrict__ wih0g,  // [2048][512] bf16
    const unsigned short* __restrict__ whh0g,
    const unsigned short* __restrict__ wc1g,   // W_ih1 @ W_out
    const unsigned short* __restrict__ whh1g,
    const unsigned short* __restrict__ w2g,    // W_out @ W_out
    const unsigned short* __restrict__ woutg,
    const float* __restrict__ b1g,
    const float* __restrict__ b2g,
    unsigned short* __restrict__ h0buf,        // [2][256][512] bf16 (parity double buffer)
    unsigned short* __restrict__ h1buf,
    unsigned int* flags1,                      // [256]
    unsigned int* flags2,
    float* __restrict__ out)                   // [T][256][512] fp32
{
  extern __shared__ char smem[];
  unsigned short* wl = (unsigned short*)smem;
  float* stg  = (float*)(smem + L_STG_B);
  float* c0L  = (float*)(smem + L_C0_B);
  float* c1L  = (float*)(smem + L_C1_B);
  float* b1sl = (float*)(smem + L_B1_B);
  float* b2sl = (float*)(smem + L_B2_B);

  const int wg = blockIdx.x;
  const int bg = wg >> 6;        // batch group (64 rows each)
  const int wn = wg & 63;        // column-slice: 8 h-cols, 32 gate-cols
  const int tid = threadIdx.x;
  const int wave = tid >> 6;
  const int lane = tid & 63;
  const int quad = lane >> 4;
  const int l16  = lane & 15;

  // ---- stage weight slices into LDS (rows packed [i(8) f(8) g(8) o(8)]) ----
  {
    const unsigned short* gsrc[4] = { wih0g, whh0g, wc1g, whh1g };
    #pragma unroll
    for (int m = 0; m < 4; m++){
      unsigned short* dst = wl + m * 16640;
      const unsigned short* src = gsrc[m];
      for (int i = tid; i < 32*512; i += 256){
        int s = i >> 9, k = i & 511;
        int gr = ((s >> 3) << 9) + wn*8 + (s & 7);
        dst[s*520 + k] = src[(size_t)gr*512 + k];
      }
    }
    const unsigned short* osrc[2] = { w2g, woutg };
    #pragma unroll
    for (int m = 0; m < 2; m++){
      unsigned short* dst = wl + L_W2 + m * 4160;
      const unsigned short* src = osrc[m];
      for (int i = tid; i < 8*512; i += 256){
        int s = i >> 9, k = i & 511;
        dst[s*520 + k] = src[(size_t)(wn*8 + s)*512 + k];
      }
    }
  }
  if (tid < 32) b1sl[tid] = b1g[((tid >> 3) << 9) + wn*8 + (tid & 7)];
  if (tid < 8)  b2sl[tid] = b2g[wn*8 + tid];
  for (int i = tid; i < 512; i += 256){ c0L[i] = 0.f; c1L[i] = 0.f; }
  __syncthreads();

  const int rowA = bg*64 + wave*16 + l16;   // A-fragment row for this lane
  const int kfo  = quad*8;                  // A/B fragment k offset

#define BF(base, nt, k0) (*(const bfrag8*)&wl[(base) + ((nt)*16 + l16)*520 + (k0) + kfo])

  // prologue: x-part of gates0 for t=0
  f32x4 xacc0 = {0.f,0.f,0.f,0.f}, xacc1 = {0.f,0.f,0.f,0.f};
  {
    const unsigned short* xr = xb + (size_t)rowA*512 + kfo;
    #pragma unroll
    for (int ks = 0; ks < 16; ks++){
      bfrag8 a = *(const bfrag8*)(xr + ks*32);
      xacc0 = mfma16(a, BF(L_WIH0, 0, ks*32), xacc0);
      xacc1 = mfma16(a, BF(L_WIH0, 1, ks*32), xacc1);
    }
  }

  bfrag8 h0f[16], h1f[16];   // register-cached activation fragments (h0'(t), h1'(t))
  const int ewr = tid & 63;
  const int ewc = (tid >> 6) * 2;
  const size_t hslice = (size_t)(bg*64)*512 + wn*8;

  for (int t = 0; t < T_STEPS; t++){
    const int par = t & 1;
    const size_t poff = (size_t)par * (BATCH*512);

    // ===== A: gates0 = xacc + h0(t-1) @ W_hh0 (h0 frags cached in regs) =====
    f32x4 g0a = xacc0, g0b = xacc1;
    if (t > 0){
      #pragma unroll
      for (int ks = 0; ks < 16; ks++){
        g0a = mfma16(h0f[ks], BF(L_WHH0, 0, ks*32), g0a);
        g0b = mfma16(h0f[ks], BF(L_WHH0, 1, ks*32), g0b);
      }
    }
    {   // stage [64x32] + LSTM elementwise -> h0' (bf16 to global), c0 (LDS)
      const int rb2 = wave*16 + quad*4;
      #pragma unroll
      for (int r = 0; r < 4; r++){
        stg[(rb2+r)*33 + l16]      = g0a[r];
        stg[(rb2+r)*33 + 16 + l16] = g0b[r];
      }
      __syncthreads();
      const float* sr = stg + ewr*33;
      float cA = c0L[ewr*8 + ewc], cB = c0L[ewr*8 + ewc + 1];
      float cnA = sigm(sr[8+ewc])  *cA + sigm(sr[ewc])  *tanh_(sr[16+ewc]);
      float cnB = sigm(sr[8+ewc+1])*cB + sigm(sr[ewc+1])*tanh_(sr[16+ewc+1]);
      c0L[ewr*8 + ewc] = cnA; c0L[ewr*8 + ewc + 1] = cnB;
      float hA = sigm(sr[24+ewc])  *tanh_(cnA);
      float hB = sigm(sr[24+ewc+1])*tanh_(cnB);
      unsigned pk = (unsigned)f2bf(hA) | ((unsigned)f2bf(hB) << 16);
      *(unsigned*)(h0buf + poff + hslice + (size_t)ewr*512 + ewc) = pk;
    }
    __builtin_amdgcn_s_waitcnt(0);
    __syncthreads();
    if (tid == 0){
      __threadfence();   // release: flush XCD L2 so h0' reaches coherence point
      __hip_atomic_store(&flags1[wg], (unsigned)(t+1), __ATOMIC_RELAXED, __HIP_MEMORY_SCOPE_AGENT);
    }

    // ===== B (off critical path): gates1 partial = B1 + h1(t-1) @ W_hh1 =====
    float bbA = b1sl[l16], bbB = b1sl[16 + l16];
    f32x4 g1a = {bbA,bbA,bbA,bbA}, g1b = {bbB,bbB,bbB,bbB};
    if (t > 0){
      #pragma unroll
      for (int ks = 0; ks < 16; ks++){
        g1a = mfma16(h1f[ks], BF(L_WHH1, 0, ks*32), g1a);
        g1b = mfma16(h1f[ks], BF(L_WHH1, 1, ks*32), g1b);
      }
    }
    // ===== C (off critical path): x-part of gates0 for t+1 =====
    if (t < T_STEPS - 1){
      f32x4 z = {0.f,0.f,0.f,0.f};
      xacc0 = z; xacc1 = z;
      const unsigned short* xr = xb + ((size_t)(t+1)*BATCH + rowA)*512 + kfo;
      #pragma unroll
      for (int ks = 0; ks < 16; ks++){
        bfrag8 a = *(const bfrag8*)(xr + ks*32);
        xacc0 = mfma16(a, BF(L_WIH0, 0, ks*32), xacc0);
        xacc1 = mfma16(a, BF(L_WIH0, 1, ks*32), xacc1);
      }
    }
    // ===== wait flag1 (h0' of whole batch-group visible) =====
    if (tid < 64){
      int spins = 0;
      while (__hip_atomic_load(&flags1[bg*64 + tid], __ATOMIC_RELAXED, __HIP_MEMORY_SCOPE_AGENT) < (unsigned)(t+1)){
        __builtin_amdgcn_s_sleep(1);
        if (++spins > (1 << 20)) break;   // hang safety
      }
    }
    if (tid == 0) __threadfence();        // acquire: invalidate L1/L2
    __syncthreads();

    // ===== D+E: one pass over h0'(t): gates1 += h0'@Wc1 ; oacc = B2 + h0'@W2 =====
    float bo = (l16 < 8) ? b2sl[l16] : 0.f;
    f32x4 oacc = {bo,bo,bo,bo};
    {
      const unsigned short* hr = h0buf + poff + (size_t)rowA*512 + kfo;
      #pragma unroll
      for (int ks = 0; ks < 16; ks++){
        h0f[ks] = *(const bfrag8*)(hr + ks*32);   // cache for next step's phase A
        g1a  = mfma16(h0f[ks], BF(L_WC1, 0, ks*32), g1a);
        g1b  = mfma16(h0f[ks], BF(L_WC1, 1, ks*32), g1b);
        oacc = mfma16(h0f[ks], BF(L_W2,  0, ks*32), oacc);
      }
    }
    {   // stage + elementwise -> h1', c1
      const int rb2 = wave*16 + quad*4;
      #pragma unroll
      for (int r = 0; r < 4; r++){
        stg[(rb2+r)*33 + l16]      = g1a[r];
        stg[(rb2+r)*33 + 16 + l16] = g1b[r];
      }
      __syncthreads();
      const float* sr = stg + ewr*33;
      float cA = c1L[ewr*8 + ewc], cB = c1L[ewr*8 + ewc + 1];
      float cnA = sigm(sr[8+ewc])  *cA + sigm(sr[ewc])  *tanh_(sr[16+ewc]);
      float cnB = sigm(sr[8+ewc+1])*cB + sigm(sr[ewc+1])*tanh_(sr[16+ewc+1]);
      c1L[ewr*8 + ewc] = cnA; c1L[ewr*8 + ewc + 1] = cnB;
      float hA = sigm(sr[24+ewc])  *tanh_(cnA);
      float hB = sigm(sr[24+ewc+1])*tanh_(cnB);
      unsigned pk = (unsigned)f2bf(hA) | ((unsigned)f2bf(hB) << 16);
      *(unsigned*)(h1buf + poff + hslice + (size_t)ewr*512 + ewc) = pk;
    }
    __builtin_amdgcn_s_waitcnt(0);
    __syncthreads();
    if (tid == 0){
      __threadfence();
      __hip_atomic_store(&flags2[wg], (unsigned)(t+1), __ATOMIC_RELAXED, __HIP_MEMORY_SCOPE_AGENT);
    }
    // ===== wait flag2 =====
    if (tid < 64){
      int spins = 0;
      while (__hip_atomic_load(&flags2[bg*64 + tid], __ATOMIC_RELAXED, __HIP_MEMORY_SCOPE_AGENT) < (unsigned)(t+1)){
        __builtin_amdgcn_s_sleep(1);
        if (++spins > (1 << 20)) break;
      }
    }
    if (tid == 0) __threadfence();
    __syncthreads();

    // ===== F: out(t) = oacc + h1'(t) @ W_out =====
    {
      const unsigned short* hr = h1buf + poff + (size_t)rowA*512 + kfo;
      #pragma unroll
      for (int ks = 0; ks < 16; ks++){
        h1f[ks] = *(const bfrag8*)(hr + ks*32);   // cache for next step's phase B
        oacc = mfma16(h1f[ks], BF(L_WOUT, 0, ks*32), oacc);
      }
    }
    if (l16 < 8){
      size_t ob = (size_t)t*(BATCH*512) + (size_t)(bg*64 + wave*16 + quad*4)*512 + wn*8 + l16;
      out[ob]        = oacc[0];
      out[ob + 512]  = oacc[1];
      out[ob + 1024] = oacc[2];
      out[ob + 1536] = oacc[3];
    }
  }
#undef BF
}

// ---------------- host ----------------
extern "C" void kernel_launch(void* const* d_in, const int* in_sizes, int n_in,
                              void* d_out, int out_size, void* d_ws, size_t ws_size,
                              hipStream_t stream){
  (void)in_sizes; (void)n_in; (void)out_size; (void)ws_size;
  const float* x    = (const float*)d_in[0];
  const float* wih0 = (const float*)d_in[1];
  const float* whh0 = (const float*)d_in[2];
  const float* wih1 = (const float*)d_in[3];
  const float* whh1 = (const float*)d_in[4];
  const float* bih1 = (const float*)d_in[5];
  const float* bhh1 = (const float*)d_in[6];
  const float* wout = (const float*)d_in[7];
  const float* bout = (const float*)d_in[8];

  char* ws = (char*)d_ws;
  size_t off = 0;
  auto alloc = [&](size_t bytes){ void* p = ws + off; off += (bytes + 255) & ~(size_t)255; return p; };
  unsigned short* xbf   = (unsigned short*)alloc(33554432);  // x bf16
  unsigned short* wih0b = (unsigned short*)alloc(2097152);
  unsigned short* whh0b = (unsigned short*)alloc(2097152);
  unsigned short* wc1b  = (unsigned short*)alloc(2097152);
  unsigned short* whh1b = (unsigned short*)alloc(2097152);
  unsigned short* w2b   = (unsigned short*)alloc(524288);
  unsigned short* woutb = (unsigned short*)alloc(524288);
  float* b1 = (float*)alloc(8192);
  float* b2 = (float*)alloc(2048);
  unsigned short* h0b = (unsigned short*)alloc(524288);
  unsigned short* h1b = (unsigned short*)alloc(524288);
  unsigned int* flags = (unsigned int*)alloc(2048);

  hipMemsetAsync(flags, 0, 2048, stream);
  cast_f32_bf16<<<16384, 256, 0, stream>>>(x, xbf, 16777216/4);
  cast_f32_bf16<<<1024, 256, 0, stream>>>(wih0, wih0b, 1048576/4);
  cast_f32_bf16<<<1024, 256, 0, stream>>>(whh0, whh0b, 1048576/4);
  cast_f32_bf16<<<1024, 256, 0, stream>>>(whh1, whh1b, 1048576/4);
  cast_f32_bf16<<<256,  256, 0, stream>>>(wout, woutb, 262144/4);
  gemm_combo<<<dim3(8,32), 256, 0, stream>>>(wih1, wout, wc1b, 2048, 512, 512);  // Wc1 = W_ih1 @ W_out
  gemm_combo<<<dim3(8,8),  256, 0, stream>>>(wout, wout, w2b,  512, 512, 512);   // W2  = W_out @ W_out
  bias_prep<<<10, 256, 0, stream>>>(wih1, bih1, bhh1, wout, bout, b1, b2);

  unsigned int* f1p = flags;
  unsigned int* f2p = flags + 256;
  float* outp = (float*)d_out;
  void* kargs[] = {
    (void*)&xbf, (void*)&wih0b, (void*)&whh0b, (void*)&wc1b, (void*)&whh1b,
    (void*)&w2b, (void*)&woutb, (void*)&b1, (void*)&b2,
    (void*)&h0b, (void*)&h1b, (void*)&f1p, (void*)&f2p, (void*)&outp
  };
  hipFuncSetAttribute((const void*)fflstm_persist,
                      hipFuncAttributeMaxDynamicSharedMemorySize, SMEM_BYTES);
  hipLaunchCooperativeKernel((const void*)fflstm_persist, dim3(256), dim3(256),
                             kargs, SMEM_BYTES, stream);
}

// Round 5
// 4622.018 us; speedup vs baseline: 1.0730x; 1.0730x over previous
//
#include <hip/hip_runtime.h>
#include <stdint.h>

#define T_STEPS 128
#define BATCH   256

typedef __attribute__((ext_vector_type(8))) short bfrag8;   // 8 x bf16
typedef __attribute__((ext_vector_type(4))) float f32x4;

// ---------------- LDS layout (persistent kernel) ----------------
#define L_WIH0 0
#define L_WHH0 16640
#define L_WC1  33280
#define L_WHH1 49920
#define L_W2   66560
#define L_WOUT 70720
#define L_STG_B 149760
#define L_C0_B  158208
#define L_C1_B  160256
#define L_B1_B  162304
#define L_B2_B  162432
#define SMEM_BYTES 162464

static __device__ __forceinline__ unsigned short f2bf(float f){
  union { float f; unsigned u; } v; v.f = f;
  return (unsigned short)((v.u + 0x7FFFu + ((v.u >> 16) & 1u)) >> 16);  // RNE
}
static __device__ __forceinline__ float sigm(float x){
  return 1.f / (1.f + __expf(-x));
}
static __device__ __forceinline__ float tanh_(float x){
  x = fminf(15.f, fmaxf(-15.f, x));
  float e = __expf(2.f * x);
  return 1.f - 2.f / (e + 1.f);
}
static __device__ __forceinline__ f32x4 mfma16(bfrag8 a, bfrag8 b, f32x4 c){
  return __builtin_amdgcn_mfma_f32_16x16x32_bf16(a, b, c, 0, 0, 0);
}

// ---------------- prep kernels (round-1-proven, verbatim) ----------------
__global__ void cast_f32_bf16(const float* __restrict__ in, unsigned short* __restrict__ out, int n4){
  int i = blockIdx.x * blockDim.x + threadIdx.x;
  if (i < n4){
    float4 v = ((const float4*)in)[i];
    ushort4 o;
    o.x = f2bf(v.x); o.y = f2bf(v.y); o.z = f2bf(v.z); o.w = f2bf(v.w);
    ((ushort4*)out)[i] = o;
  }
}

__global__ void __launch_bounds__(256) gemm_combo(const float* __restrict__ A, const float* __restrict__ B,
                                                  unsigned short* __restrict__ C, int M, int N, int K){
  __shared__ float As[64][17];
  __shared__ float Bs[16][68];
  int col0 = blockIdx.x * 64;
  int row0 = blockIdx.y * 64;
  int tid = threadIdx.x;
  int tx = tid & 15, ty = tid >> 4;
  float acc[4][4] = {};
  for (int kp = 0; kp < K; kp += 16){
    for (int i = tid; i < 64*16; i += 256){
      int r = i >> 4, c = i & 15;
      As[r][c] = A[(size_t)(row0 + r) * K + kp + c];
    }
    for (int i = tid; i < 16*64; i += 256){
      int r = i >> 6, c = i & 63;
      Bs[r][c] = B[(size_t)(kp + r) * N + col0 + c];
    }
    __syncthreads();
    #pragma unroll
    for (int kk = 0; kk < 16; kk++){
      float a[4], b[4];
      #pragma unroll
      for (int i = 0; i < 4; i++) a[i] = As[ty*4 + i][kk];
      #pragma unroll
      for (int j = 0; j < 4; j++) b[j] = Bs[kk][tx*4 + j];
      #pragma unroll
      for (int i = 0; i < 4; i++)
        #pragma unroll
        for (int j = 0; j < 4; j++) acc[i][j] += a[i] * b[j];
    }
    __syncthreads();
  }
  for (int i = 0; i < 4; i++)
    for (int j = 0; j < 4; j++)
      C[(size_t)(row0 + ty*4 + i) * N + col0 + tx*4 + j] = f2bf(acc[i][j]);
}

__global__ void bias_prep(const float* __restrict__ wih1, const float* __restrict__ bih,
                          const float* __restrict__ bhh, const float* __restrict__ wout,
                          const float* __restrict__ bout, float* __restrict__ B1, float* __restrict__ B2){
  int t = blockIdx.x * blockDim.x + threadIdx.x;
  if (t < 2048){
    float s = bih[t] + bhh[t];
    for (int k = 0; k < 512; k++) s += wih1[(size_t)t*512 + k] * bout[k];
    B1[t] = s;
  } else if (t < 2560){
    int n = t - 2048;
    float s = bout[n];
    for (int k = 0; k < 512; k++) s += wout[(size_t)n*512 + k] * bout[k];
    B2[n] = s;
  }
}

// ---------------- persistent recurrence kernel ----------------
// ROUND-1 kernel with ONE change: phase F (wait flag2 + h1 gather + out store) for
// step t is deferred to iteration t+1, right after pub1 — removing the second
// fence+wait round-trip from the per-step critical cycle. Everything else verbatim.
__global__ void __launch_bounds__(256, 1) fflstm_persist(
    const unsigned short* __restrict__ xb,     // [T][256][512] bf16
    const unsigned short* __restrict__ wih0g,
    const unsigned short* __restrict__ whh0g,
    const unsigned short* __restrict__ wc1g,   // W_ih1 @ W_out
    const unsigned short* __restrict__ whh1g,
    const unsigned short* __restrict__ w2g,    // W_out @ W_out
    const unsigned short* __restrict__ woutg,
    const float* __restrict__ b1g,
    const float* __restrict__ b2g,
    unsigned short* __restrict__ h0buf,        // [2][256][512] bf16 parity buffers
    unsigned short* __restrict__ h1buf,
    unsigned int* flags1,                      // [256]
    unsigned int* flags2,
    float* __restrict__ out)                   // [T][256][512] fp32
{
  extern __shared__ char smem[];
  unsigned short* wl = (unsigned short*)smem;
  float* stg  = (float*)(smem + L_STG_B);
  float* c0L  = (float*)(smem + L_C0_B);
  float* c1L  = (float*)(smem + L_C1_B);
  float* b1sl = (float*)(smem + L_B1_B);
  float* b2sl = (float*)(smem + L_B2_B);

  const int wg = blockIdx.x;
  const int bg = wg >> 6;        // batch group (64 rows each) — round-1 mapping
  const int wn = wg & 63;        // column-slice: 8 h-cols, 32 gate-cols
  const int tid = threadIdx.x;
  const int wave = tid >> 6;
  const int lane = tid & 63;
  const int quad = lane >> 4;
  const int l16  = lane & 15;

  // ---- stage weight slices into LDS (rows packed [i(8) f(8) g(8) o(8)]) ----
  {
    const unsigned short* gsrc[4] = { wih0g, whh0g, wc1g, whh1g };
    #pragma unroll
    for (int m = 0; m < 4; m++){
      unsigned short* dst = wl + m * 16640;
      const unsigned short* src = gsrc[m];
      for (int i = tid; i < 32*512; i += 256){
        int s = i >> 9, k = i & 511;
        int gr = ((s >> 3) << 9) + wn*8 + (s & 7);
        dst[s*520 + k] = src[(size_t)gr*512 + k];
      }
    }
    const unsigned short* osrc[2] = { w2g, woutg };
    #pragma unroll
    for (int m = 0; m < 2; m++){
      unsigned short* dst = wl + L_W2 + m * 4160;
      const unsigned short* src = osrc[m];
      for (int i = tid; i < 8*512; i += 256){
        int s = i >> 9, k = i & 511;
        dst[s*520 + k] = src[(size_t)(wn*8 + s)*512 + k];
      }
    }
  }
  if (tid < 32) b1sl[tid] = b1g[((tid >> 3) << 9) + wn*8 + (tid & 7)];
  if (tid < 8)  b2sl[tid] = b2g[wn*8 + tid];
  for (int i = tid; i < 512; i += 256){ c0L[i] = 0.f; c1L[i] = 0.f; }
  __syncthreads();

  const int rowA = bg*64 + wave*16 + l16;   // A-fragment row for this lane
  const int kfo  = quad*8;                  // A/B fragment k offset

#define BF(base, nt, k0) (*(const bfrag8*)&wl[(base) + ((nt)*16 + l16)*520 + (k0) + kfo])

  // prologue: x-part of gates0 for t=0
  f32x4 xacc0 = {0.f,0.f,0.f,0.f}, xacc1 = {0.f,0.f,0.f,0.f};
  {
    const unsigned short* xr = xb + (size_t)rowA*512 + kfo;
    #pragma unroll
    for (int ks = 0; ks < 16; ks++){
      bfrag8 a = *(const bfrag8*)(xr + ks*32);
      xacc0 = mfma16(a, BF(L_WIH0, 0, ks*32), xacc0);
      xacc1 = mfma16(a, BF(L_WIH0, 1, ks*32), xacc1);
    }
  }

  bfrag8 h0f[16], h1f[16];   // register-cached activation fragments
  f32x4 oacc = {0.f,0.f,0.f,0.f};   // loop-carried: out-partial of step t-1
  const int ewr = tid & 63;
  const int ewc = (tid >> 6) * 2;
  const size_t hslice = (size_t)(bg*64)*512 + wn*8;

  for (int t = 0; t <= T_STEPS; t++){
    const int par = t & 1;
    const size_t poff = (size_t)par * (BATCH*512);

    // ===== A: gates0 = xacc + h0(t-1) @ W_hh0 (h0 frags cached in regs) =====
    if (t < T_STEPS){
      f32x4 g0a = xacc0, g0b = xacc1;
      if (t > 0){
        #pragma unroll
        for (int ks = 0; ks < 16; ks++){
          g0a = mfma16(h0f[ks], BF(L_WHH0, 0, ks*32), g0a);
          g0b = mfma16(h0f[ks], BF(L_WHH0, 1, ks*32), g0b);
        }
      }
      {   // stage [64x32] + LSTM elementwise -> h0' (bf16 to global), c0 (LDS)
        const int rb2 = wave*16 + quad*4;
        #pragma unroll
        for (int r = 0; r < 4; r++){
          stg[(rb2+r)*33 + l16]      = g0a[r];
          stg[(rb2+r)*33 + 16 + l16] = g0b[r];
        }
        __syncthreads();
        const float* sr = stg + ewr*33;
        float cA = c0L[ewr*8 + ewc], cB = c0L[ewr*8 + ewc + 1];
        float cnA = sigm(sr[8+ewc])  *cA + sigm(sr[ewc])  *tanh_(sr[16+ewc]);
        float cnB = sigm(sr[8+ewc+1])*cB + sigm(sr[ewc+1])*tanh_(sr[16+ewc+1]);
        c0L[ewr*8 + ewc] = cnA; c0L[ewr*8 + ewc + 1] = cnB;
        float hA = sigm(sr[24+ewc])  *tanh_(cnA);
        float hB = sigm(sr[24+ewc+1])*tanh_(cnB);
        unsigned pk = (unsigned)f2bf(hA) | ((unsigned)f2bf(hB) << 16);
        *(unsigned*)(h0buf + poff + hslice + (size_t)ewr*512 + ewc) = pk;
      }
      __builtin_amdgcn_s_waitcnt(0);
      __syncthreads();
      if (tid == 0){
        __threadfence();   // release: flush XCD L2 so h0' reaches coherence point
        __hip_atomic_store(&flags1[wg], (unsigned)(t+1), __ATOMIC_RELAXED, __HIP_MEMORY_SCOPE_AGENT);
      }
    }

    // ===== F (deferred from step t-1): wait flag2; out(t-1) = oacc + h1'(t-1)@Wout =====
    if (t >= 1){
      if (tid < 64){
        int spins = 0;
        while (__hip_atomic_load(&flags2[bg*64 + tid], __ATOMIC_RELAXED, __HIP_MEMORY_SCOPE_AGENT) < (unsigned)t){
          __builtin_amdgcn_s_sleep(1);
          if (++spins > (1 << 20)) break;
        }
      }
      if (tid == 0) __threadfence();
      __syncthreads();
      {
        const unsigned short* hr = h1buf + (size_t)((t-1)&1)*(BATCH*512) + (size_t)rowA*512 + kfo;
        #pragma unroll
        for (int ks = 0; ks < 16; ks++){
          h1f[ks] = *(const bfrag8*)(hr + ks*32);   // cache for this step's phase B
          oacc = mfma16(h1f[ks], BF(L_WOUT, 0, ks*32), oacc);
        }
      }
      if (l16 < 8){
        size_t ob = (size_t)(t-1)*(BATCH*512) + (size_t)(bg*64 + wave*16 + quad*4)*512 + wn*8 + l16;
        out[ob]        = oacc[0];
        out[ob + 512]  = oacc[1];
        out[ob + 1024] = oacc[2];
        out[ob + 1536] = oacc[3];
      }
    }

    if (t < T_STEPS){
      // ===== B (off critical path): gates1 partial = B1 + h1(t-1) @ W_hh1 =====
      float bbA = b1sl[l16], bbB = b1sl[16 + l16];
      f32x4 g1a = {bbA,bbA,bbA,bbA}, g1b = {bbB,bbB,bbB,bbB};
      if (t > 0){
        #pragma unroll
        for (int ks = 0; ks < 16; ks++){
          g1a = mfma16(h1f[ks], BF(L_WHH1, 0, ks*32), g1a);
          g1b = mfma16(h1f[ks], BF(L_WHH1, 1, ks*32), g1b);
        }
      }
      // ===== C (off critical path): x-part of gates0 for t+1 =====
      if (t < T_STEPS - 1){
        f32x4 z = {0.f,0.f,0.f,0.f};
        xacc0 = z; xacc1 = z;
        const unsigned short* xr = xb + ((size_t)(t+1)*BATCH + rowA)*512 + kfo;
        #pragma unroll
        for (int ks = 0; ks < 16; ks++){
          bfrag8 a = *(const bfrag8*)(xr + ks*32);
          xacc0 = mfma16(a, BF(L_WIH0, 0, ks*32), xacc0);
          xacc1 = mfma16(a, BF(L_WIH0, 1, ks*32), xacc1);
        }
      }
      // ===== wait flag1 (h0' of whole batch-group visible) =====
      if (tid < 64){
        int spins = 0;
        while (__hip_atomic_load(&flags1[bg*64 + tid], __ATOMIC_RELAXED, __HIP_MEMORY_SCOPE_AGENT) < (unsigned)(t+1)){
          __builtin_amdgcn_s_sleep(1);
          if (++spins > (1 << 20)) break;   // hang safety
        }
      }
      if (tid == 0) __threadfence();        // acquire: invalidate L1/L2
      __syncthreads();

      // ===== D+E: one pass over h0'(t): gates1 += h0'@Wc1 ; oacc = B2 + h0'@W2 =====
      float bo = (l16 < 8) ? b2sl[l16] : 0.f;
      oacc[0] = bo; oacc[1] = bo; oacc[2] = bo; oacc[3] = bo;
      {
        const unsigned short* hr = h0buf + poff + (size_t)rowA*512 + kfo;
        #pragma unroll
        for (int ks = 0; ks < 16; ks++){
          h0f[ks] = *(const bfrag8*)(hr + ks*32);   // cache for next step's phase A
          g1a  = mfma16(h0f[ks], BF(L_WC1, 0, ks*32), g1a);
          g1b  = mfma16(h0f[ks], BF(L_WC1, 1, ks*32), g1b);
          oacc = mfma16(h0f[ks], BF(L_W2,  0, ks*32), oacc);
        }
      }
      {   // stage + elementwise -> h1', c1
        const int rb2 = wave*16 + quad*4;
        #pragma unroll
        for (int r = 0; r < 4; r++){
          stg[(rb2+r)*33 + l16]      = g1a[r];
          stg[(rb2+r)*33 + 16 + l16] = g1b[r];
        }
        __syncthreads();
        const float* sr = stg + ewr*33;
        float cA = c1L[ewr*8 + ewc], cB = c1L[ewr*8 + ewc + 1];
        float cnA = sigm(sr[8+ewc])  *cA + sigm(sr[ewc])  *tanh_(sr[16+ewc]);
        float cnB = sigm(sr[8+ewc+1])*cB + sigm(sr[ewc+1])*tanh_(sr[16+ewc+1]);
        c1L[ewr*8 + ewc] = cnA; c1L[ewr*8 + ewc + 1] = cnB;
        float hA = sigm(sr[24+ewc])  *tanh_(cnA);
        float hB = sigm(sr[24+ewc+1])*tanh_(cnB);
        unsigned pk = (unsigned)f2bf(hA) | ((unsigned)f2bf(hB) << 16);
        *(unsigned*)(h1buf + poff + hslice + (size_t)ewr*512 + ewc) = pk;
      }
      __builtin_amdgcn_s_waitcnt(0);
      __syncthreads();
      if (tid == 0){
        __threadfence();
        __hip_atomic_store(&flags2[wg], (unsigned)(t+1), __ATOMIC_RELAXED, __HIP_MEMORY_SCOPE_AGENT);
      }
    }
  }
#undef BF
}

// ---------------- host (round-1 verbatim) ----------------
extern "C" void kernel_launch(void* const* d_in, const int* in_sizes, int n_in,
                              void* d_out, int out_size, void* d_ws, size_t ws_size,
                              hipStream_t stream){
  (void)in_sizes; (void)n_in; (void)out_size; (void)ws_size;
  const float* x    = (const float*)d_in[0];
  const float* wih0 = (const float*)d_in[1];
  const float* whh0 = (const float*)d_in[2];
  const float* wih1 = (const float*)d_in[3];
  const float* whh1 = (const float*)d_in[4];
  const float* bih1 = (const float*)d_in[5];
  const float* bhh1 = (const float*)d_in[6];
  const float* wout = (const float*)d_in[7];
  const float* bout = (const float*)d_in[8];

  char* ws = (char*)d_ws;
  size_t off = 0;
  auto alloc = [&](size_t bytes){ void* p = ws + off; off += (bytes + 255) & ~(size_t)255; return p; };
  unsigned short* xbf   = (unsigned short*)alloc(33554432);  // x bf16
  unsigned short* wih0b = (unsigned short*)alloc(2097152);
  unsigned short* whh0b = (unsigned short*)alloc(2097152);
  unsigned short* wc1b  = (unsigned short*)alloc(2097152);
  unsigned short* whh1b = (unsigned short*)alloc(2097152);
  unsigned short* w2b   = (unsigned short*)alloc(524288);
  unsigned short* woutb = (unsigned short*)alloc(524288);
  float* b1 = (float*)alloc(8192);
  float* b2 = (float*)alloc(2048);
  unsigned short* h0b = (unsigned short*)alloc(524288);
  unsigned short* h1b = (unsigned short*)alloc(524288);
  unsigned int* flags = (unsigned int*)alloc(2048);

  hipMemsetAsync(flags, 0, 2048, stream);
  cast_f32_bf16<<<16384, 256, 0, stream>>>(x, xbf, 16777216/4);
  cast_f32_bf16<<<1024, 256, 0, stream>>>(wih0, wih0b, 1048576/4);
  cast_f32_bf16<<<1024, 256, 0, stream>>>(whh0, whh0b, 1048576/4);
  cast_f32_bf16<<<1024, 256, 0, stream>>>(whh1, whh1b, 1048576/4);
  cast_f32_bf16<<<256,  256, 0, stream>>>(wout, woutb, 262144/4);
  gemm_combo<<<dim3(8,32), 256, 0, stream>>>(wih1, wout, wc1b, 2048, 512, 512);  // Wc1 = W_ih1 @ W_out
  gemm_combo<<<dim3(8,8),  256, 0, stream>>>(wout, wout, w2b,  512, 512, 512);   // W2  = W_out @ W_out
  bias_prep<<<10, 256, 0, stream>>>(wih1, bih1, bhh1, wout, bout, b1, b2);

  unsigned int* f1p = flags;
  unsigned int* f2p = flags + 256;
  float* outp = (float*)d_out;
  void* kargs[] = {
    (void*)&xbf, (void*)&wih0b, (void*)&whh0b, (void*)&wc1b, (void*)&whh1b,
    (void*)&w2b, (void*)&woutb, (void*)&b1, (void*)&b2,
    (void*)&h0b, (void*)&h1b, (void*)&f1p, (void*)&f2p, (void*)&outp
  };
  hipFuncSetAttribute((const void*)fflstm_persist,
                      hipFuncAttributeMaxDynamicSharedMemorySize, SMEM_BYTES);
  hipLaunchCooperativeKernel((const void*)fflstm_persist, dim3(256), dim3(256),
                             kargs, SMEM_BYTES, stream);
}